// Round 1
// baseline (359.125 us; speedup 1.0000x reference)
//
#include <hip/hip_runtime.h>
#include <hip/hip_bf16.h>
#include <stdint.h>

#define N_ROWS 16384
#define M_ROWS 4096
#define DDIM   512
#define BK     32
#define NKT    (DDIM / BK)   // 16 K-tiles

using frag_ab = __attribute__((ext_vector_type(8))) short;  // 8 bf16 (4 VGPRs)
using frag_cd = __attribute__((ext_vector_type(4))) float;  // 4 fp32 acc

__device__ __forceinline__ unsigned short f2bf(float f) {
  unsigned int u = __float_as_uint(f);
  u += 0x7fffu + ((u >> 16) & 1u);   // round-to-nearest-even
  return (unsigned short)(u >> 16);
}

// One wave per row: fp32 -> bf16 conversion + fp32 row-norm.
__global__ void rbf_convert_kernel(const float* __restrict__ in,
                                   const float* __restrict__ cen,
                                   unsigned short* __restrict__ a_bf,
                                   unsigned short* __restrict__ b_bf,
                                   float* __restrict__ x_sq,
                                   float* __restrict__ c_sq) {
  const int wave = threadIdx.x >> 6;
  const int lane = threadIdx.x & 63;
  const int row  = blockIdx.x * 4 + wave;

  const float* src;
  unsigned short* dst;
  float* nrm;
  if (row < N_ROWS) {
    src = in + (long)row * DDIM;
    dst = a_bf + (long)row * DDIM;
    nrm = x_sq + row;
  } else {
    const int rr = row - N_ROWS;
    src = cen + (long)rr * DDIM;
    dst = b_bf + (long)rr * DDIM;
    nrm = c_sq + rr;
  }

  float sum = 0.f;
#pragma unroll
  for (int it = 0; it < 2; ++it) {
    const int col = it * 256 + lane * 4;
    float4 v = *(const float4*)(src + col);
    sum += v.x * v.x + v.y * v.y + v.z * v.z + v.w * v.w;
    ushort4 p;
    p.x = f2bf(v.x); p.y = f2bf(v.y); p.z = f2bf(v.z); p.w = f2bf(v.w);
    *(ushort4*)(dst + col) = p;
  }
#pragma unroll
  for (int off = 32; off > 0; off >>= 1) sum += __shfl_down(sum, off, 64);
  if (lane == 0) *nrm = sum;
}

// 256x256-tile GEMM-with-epilogue: out = x_sq + c_sq - 2 * (A . B^T)
// 8 waves (2 n-halves x 4 m-quarters), each owning a 128x64 output subtile
// (8x4 fragments of 16x16). BK=32, QUAD-buffered LDS (4 slots x 32 KiB =
// 128 KiB) with counted s_waitcnt vmcnt(8) -- 3 K-tiles of global_load_lds
// in flight, never drained to 0 in steady state (T3+T4). One barrier per
// K-tile (32 MFMA/wave between barriers). LDS XOR-swizzle (T2) via
// pre-swizzled global source + swizzled ds_read (involution byte^=(byte>>3)&48).
// s_setprio around MFMA cluster (T5). XCD-bijective block swizzle (T1).
// Nontemporal epilogue stores keep the 268 MB output stream from evicting
// the 20 MiB bf16 operand panels out of L2/L3.
__global__ __launch_bounds__(512, 2) void rbf_gemm_kernel(
    const unsigned short* __restrict__ a_bf,
    const unsigned short* __restrict__ b_bf,
    const float* __restrict__ x_sq,
    const float* __restrict__ c_sq,
    float* __restrict__ out) {
  // 4 slots, each [256 rows][32 bf16] = 16 KiB per operand.
  __shared__ __attribute__((aligned(16))) unsigned short A_lds[4][256 * BK];
  __shared__ __attribute__((aligned(16))) unsigned short B_lds[4][256 * BK];

  const int tid    = threadIdx.x;
  const int wid    = tid >> 6;
  const int lane   = tid & 63;
  const int lane15 = lane & 15;
  const int quad   = lane >> 4;
  const int wm     = wid >> 2;  // 0..1 : which 128-row (n) half
  const int wn     = wid & 3;   // 0..3 : which 64-col (m) quarter

  // XCD-aware bijective swizzle (1024 blocks % 8 XCDs == 0): each XCD gets
  // 8 consecutive by-rows with bx fast -> 256 KiB A-panel L2-resident.
  const int orig = blockIdx.x;
  const int wg   = (orig & 7) * 128 + (orig >> 3);
  const int m0   = (wg & 15) * 256;   // 16 m-tiles
  const int n0   = (wg >> 4) * 256;   // 64 n-tiles

  // Staging addresses. Linear LDS dest chunk c = it*512+tid (16 B each);
  // source is the INVERSE-swizzled logical offset (XOR is an involution):
  //   o' = o ^ ((o>>3)&48)   (row bits 1-2 -> byte bits 4-5)
  const unsigned short* srcA[2];
  const unsigned short* srcB[2];
  int dstc[2];
#pragma unroll
  for (int it = 0; it < 2; ++it) {
    const int o   = (it * 512 + tid) * 16;       // linear byte offset in slot
    const int op  = o ^ ((o >> 3) & 48);         // swizzled logical offset
    const int row = op >> 6;                     // 64 B rows
    const int ke  = (op & 63) >> 1;              // element offset in row
    srcA[it] = a_bf + (size_t)(n0 + row) * DDIM + ke;
    srcB[it] = b_bf + (size_t)(m0 + row) * DDIM + ke;
    dstc[it] = (it * 512 + tid) * 8;             // ushort index (16 B chunks)
  }

  // Fragment LDS byte offsets within a slot (kt-independent), swizzled read.
  int offA[8], offB[4];
#pragma unroll
  for (int i = 0; i < 8; ++i) {
    const int row = wm * 128 + i * 16 + lane15;
    const int L   = row * 64 + quad * 16;
    offA[i] = L ^ ((L >> 3) & 48);
  }
#pragma unroll
  for (int j = 0; j < 4; ++j) {
    const int row = wn * 64 + j * 16 + lane15;
    const int L   = row * 64 + quad * 16;
    offB[j] = L ^ ((L >> 3) & 48);
  }

  frag_cd acc[8][4];
#pragma unroll
  for (int i = 0; i < 8; ++i)
#pragma unroll
    for (int j = 0; j < 4; ++j)
      acc[i][j] = (frag_cd){0.f, 0.f, 0.f, 0.f};

  auto stage = [&](int slot, int kt) {
#pragma unroll
    for (int it = 0; it < 2; ++it) {
      __builtin_amdgcn_global_load_lds(
          (const __attribute__((address_space(1))) unsigned int*)(srcA[it] + kt * BK),
          (__attribute__((address_space(3))) unsigned int*)&A_lds[slot][dstc[it]],
          16, 0, 0);
      __builtin_amdgcn_global_load_lds(
          (const __attribute__((address_space(1))) unsigned int*)(srcB[it] + kt * BK),
          (__attribute__((address_space(3))) unsigned int*)&B_lds[slot][dstc[it]],
          16, 0, 0);
    }
  };

  // Prologue: 3 K-tiles in flight (12 VMEM instrs/wave).
  stage(0, 0);
  stage(1, 1);
  stage(2, 2);

#pragma unroll
  for (int kt = 0; kt < NKT; ++kt) {
    // Per-wave counted wait: retire THIS K-tile's 4 loads, leave the 8
    // newer ones (kt+1, kt+2) in flight. Then barrier: every wave has
    // passed its own vmcnt, so all writes for kt have landed workgroup-wide.
    if (kt <= NKT - 3)      asm volatile("s_waitcnt vmcnt(8)" ::: "memory");
    else if (kt == NKT - 2) asm volatile("s_waitcnt vmcnt(4)" ::: "memory");
    else                    asm volatile("s_waitcnt vmcnt(0)" ::: "memory");
    __builtin_amdgcn_s_barrier();
    __builtin_amdgcn_sched_barrier(0);  // pin: nothing crosses the K-tile edge

    // Issue next prefetch early: slot (kt+3)&3 was last read in K-tile kt-1,
    // and every wave has passed that read (the barrier above).
    if (kt + 3 < NKT) stage((kt + 3) & 3, kt + 3);

    const char* Ab = (const char*)&A_lds[kt & 3][0];
    const char* Bb = (const char*)&B_lds[kt & 3][0];
    frag_ab a[8], b[4];
#pragma unroll
    for (int j = 0; j < 4; ++j) b[j] = *(const frag_ab*)(Bb + offB[j]);
#pragma unroll
    for (int i = 0; i < 8; ++i) a[i] = *(const frag_ab*)(Ab + offA[i]);

    __builtin_amdgcn_s_setprio(1);
#pragma unroll
    for (int i = 0; i < 8; ++i)
#pragma unroll
      for (int j = 0; j < 4; ++j)
        acc[i][j] = __builtin_amdgcn_mfma_f32_16x16x32_bf16(
            a[i], b[j], acc[i][j], 0, 0, 0);
    __builtin_amdgcn_s_setprio(0);
  }

  // Epilogue: out[r][c] = x_sq[r] + c_sq[c] - 2*dot.
  // C/D layout: col = lane&15, row = quad*4 + reg (m89-verified).
  float cs[4];
#pragma unroll
  for (int j = 0; j < 4; ++j) cs[j] = c_sq[m0 + wn * 64 + j * 16 + lane15];

#pragma unroll
  for (int i = 0; i < 8; ++i) {
#pragma unroll
    for (int reg = 0; reg < 4; ++reg) {
      const int r = n0 + wm * 128 + i * 16 + quad * 4 + reg;
      const float xv = x_sq[r];
      float* orow = out + (size_t)r * M_ROWS + m0 + wn * 64 + lane15;
#pragma unroll
      for (int j = 0; j < 4; ++j) {
        __builtin_nontemporal_store(xv + cs[j] - 2.0f * acc[i][j][reg],
                                    orow + j * 16);
      }
    }
  }
}

extern "C" void kernel_launch(void* const* d_in, const int* in_sizes, int n_in,
                              void* d_out, int out_size, void* d_ws, size_t ws_size,
                              hipStream_t stream) {
  const float* input   = (const float*)d_in[0];
  const float* centres = (const float*)d_in[1];
  float* out = (float*)d_out;

  // Workspace layout (~20.1 MB):
  //   a_bf: N*D bf16 (16 MiB) | b_bf: M*D bf16 (4 MiB) | x_sq: N f32 | c_sq: M f32
  char* ws = (char*)d_ws;
  unsigned short* a_bf = (unsigned short*)ws;
  unsigned short* b_bf = (unsigned short*)(ws + (size_t)N_ROWS * DDIM * 2);
  float* x_sq = (float*)(ws + (size_t)N_ROWS * DDIM * 2 + (size_t)M_ROWS * DDIM * 2);
  float* c_sq = x_sq + N_ROWS;

  rbf_convert_kernel<<<(N_ROWS + M_ROWS) / 4, 256, 0, stream>>>(
      input, centres, a_bf, b_bf, x_sq, c_sq);

  rbf_gemm_kernel<<<(N_ROWS / 256) * (M_ROWS / 256), 512, 0, stream>>>(
      a_bf, b_bf, x_sq, c_sq, out);
}

// Round 2
// 356.629 us; speedup vs baseline: 1.0070x; 1.0070x over previous
//
#include <hip/hip_runtime.h>
#include <hip/hip_bf16.h>
#include <stdint.h>

#define N_ROWS 16384
#define M_ROWS 4096
#define DDIM   512
#define BK     32
#define NKT    (DDIM / BK)   // 16 K-tiles

using frag_ab = __attribute__((ext_vector_type(8))) short;  // 8 bf16 (4 VGPRs)
using frag_cd = __attribute__((ext_vector_type(4))) float;  // 4 fp32 acc

__device__ __forceinline__ unsigned short f2bf(float f) {
  unsigned int u = __float_as_uint(f);
  u += 0x7fffu + ((u >> 16) & 1u);   // round-to-nearest-even
  return (unsigned short)(u >> 16);
}

// One wave per row: fp32 -> bf16 conversion + fp32 row-norm.
__global__ void rbf_convert_kernel(const float* __restrict__ in,
                                   const float* __restrict__ cen,
                                   unsigned short* __restrict__ a_bf,
                                   unsigned short* __restrict__ b_bf,
                                   float* __restrict__ x_sq,
                                   float* __restrict__ c_sq) {
  const int wave = threadIdx.x >> 6;
  const int lane = threadIdx.x & 63;
  const int row  = blockIdx.x * 4 + wave;

  const float* src;
  unsigned short* dst;
  float* nrm;
  if (row < N_ROWS) {
    src = in + (long)row * DDIM;
    dst = a_bf + (long)row * DDIM;
    nrm = x_sq + row;
  } else {
    const int rr = row - N_ROWS;
    src = cen + (long)rr * DDIM;
    dst = b_bf + (long)rr * DDIM;
    nrm = c_sq + rr;
  }

  float sum = 0.f;
#pragma unroll
  for (int it = 0; it < 2; ++it) {
    const int col = it * 256 + lane * 4;
    float4 v = *(const float4*)(src + col);
    sum += v.x * v.x + v.y * v.y + v.z * v.z + v.w * v.w;
    ushort4 p;
    p.x = f2bf(v.x); p.y = f2bf(v.y); p.z = f2bf(v.z); p.w = f2bf(v.w);
    *(ushort4*)(dst + col) = p;
  }
#pragma unroll
  for (int off = 32; off > 0; off >>= 1) sum += __shfl_down(sum, off, 64);
  if (lane == 0) *nrm = sum;
}

// 256x256-tile GEMM-with-epilogue: out = x_sq + c_sq - 2 * (A . B^T)
// 8 waves (2 n-halves x 4 m-quarters), each owning a 128x64 output subtile.
// BK=32 quad-buffered LDS, counted s_waitcnt vmcnt(8) pipeline (T3+T4),
// LDS XOR-swizzle (T2), setprio (T5).
//
// CACHE-SHAPING (the round-2 change): round-1's m-fast ordering swept the
// full 4 MB B panel through each 4 MiB XCD-L2 per A-tile (working set
// 4.25 MB -> thrash; ~500 MB of re-reads fell to L3/HBM behind a 268 MB
// write stream => memory-bound, schedule-insensitive). Now each XCD
// (orig&7) owns an 8-n-tile band (2 MB of A rows) and walks m slowly:
// 8 consecutive blocks share one 256 KB B m-tile across distinct n.
// Working set 2.25 MB < 4 MB L2: A-band loads from HBM once per XCD and
// re-reads 16x from L2; B m-tiles advance in lockstep across XCDs (L3-
// shared). Predicted: GEMM FETCH_SIZE drops ~10-20x, dur -> write-floor.
// Stores are PLAIN (not nontemporal): each store instr = 4 full 64 B
// lines (16 consecutive lanes x 4 quads), perfectly coalesced via L2.
__global__ __launch_bounds__(512, 2) void rbf_gemm_kernel(
    const unsigned short* __restrict__ a_bf,
    const unsigned short* __restrict__ b_bf,
    const float* __restrict__ x_sq,
    const float* __restrict__ c_sq,
    float* __restrict__ out) {
  __shared__ __attribute__((aligned(16))) unsigned short A_lds[4][256 * BK];
  __shared__ __attribute__((aligned(16))) unsigned short B_lds[4][256 * BK];

  const int tid    = threadIdx.x;
  const int wid    = tid >> 6;
  const int lane   = tid & 63;
  const int lane15 = lane & 15;
  const int quad   = lane >> 4;
  const int wm     = wid >> 2;  // 0..1 : which 128-row (n) half
  const int wn     = wid & 3;   // 0..3 : which 64-col (m) quarter

  // XCD-banded, n-fast mapping (bijective over 16 m-tiles x 64 n-tiles):
  //   xcd = orig&7 owns n-tiles [xcd*8, xcd*8+8); s>>3 walks m slowly.
  const int orig = blockIdx.x;      // 0..1023
  const int xcd  = orig & 7;
  const int s    = orig >> 3;       // 0..127 within XCD
  const int m0   = (s >> 3) * 256;          // 16 m-tiles, slow
  const int n0   = (xcd * 8 + (s & 7)) * 256;  // 64 n-tiles, fast within band

  // Staging: linear LDS dest chunk c = it*512+tid (16 B); global source is
  // the INVERSE-swizzled logical offset (XOR involution o^=(o>>3)&48).
  const unsigned short* srcA[2];
  const unsigned short* srcB[2];
  int dstc[2];
#pragma unroll
  for (int it = 0; it < 2; ++it) {
    const int o   = (it * 512 + tid) * 16;
    const int op  = o ^ ((o >> 3) & 48);
    const int row = op >> 6;
    const int ke  = (op & 63) >> 1;
    srcA[it] = a_bf + (size_t)(n0 + row) * DDIM + ke;
    srcB[it] = b_bf + (size_t)(m0 + row) * DDIM + ke;
    dstc[it] = (it * 512 + tid) * 8;
  }

  // Fragment LDS byte offsets (kt-independent), swizzled read.
  int offA[8], offB[4];
#pragma unroll
  for (int i = 0; i < 8; ++i) {
    const int row = wm * 128 + i * 16 + lane15;
    const int L   = row * 64 + quad * 16;
    offA[i] = L ^ ((L >> 3) & 48);
  }
#pragma unroll
  for (int j = 0; j < 4; ++j) {
    const int row = wn * 64 + j * 16 + lane15;
    const int L   = row * 64 + quad * 16;
    offB[j] = L ^ ((L >> 3) & 48);
  }

  frag_cd acc[8][4];
#pragma unroll
  for (int i = 0; i < 8; ++i)
#pragma unroll
    for (int j = 0; j < 4; ++j)
      acc[i][j] = (frag_cd){0.f, 0.f, 0.f, 0.f};

  auto stage = [&](int slot, int kt) {
#pragma unroll
    for (int it = 0; it < 2; ++it) {
      __builtin_amdgcn_global_load_lds(
          (const __attribute__((address_space(1))) unsigned int*)(srcA[it] + kt * BK),
          (__attribute__((address_space(3))) unsigned int*)&A_lds[slot][dstc[it]],
          16, 0, 0);
      __builtin_amdgcn_global_load_lds(
          (const __attribute__((address_space(1))) unsigned int*)(srcB[it] + kt * BK),
          (__attribute__((address_space(3))) unsigned int*)&B_lds[slot][dstc[it]],
          16, 0, 0);
    }
  };

  // Prologue: 3 K-tiles in flight (12 VMEM instrs/wave).
  stage(0, 0);
  stage(1, 1);
  stage(2, 2);

#pragma unroll
  for (int kt = 0; kt < NKT; ++kt) {
    // Counted per-wave wait (retire this K-tile's 4 loads, keep 8 newer in
    // flight), then barrier -> workgroup-wide visibility for slot kt&3.
    if (kt <= NKT - 3)      asm volatile("s_waitcnt vmcnt(8)" ::: "memory");
    else if (kt == NKT - 2) asm volatile("s_waitcnt vmcnt(4)" ::: "memory");
    else                    asm volatile("s_waitcnt vmcnt(0)" ::: "memory");
    __builtin_amdgcn_s_barrier();
    __builtin_amdgcn_sched_barrier(0);

    if (kt + 3 < NKT) stage((kt + 3) & 3, kt + 3);

    const char* Ab = (const char*)&A_lds[kt & 3][0];
    const char* Bb = (const char*)&B_lds[kt & 3][0];
    frag_ab a[8], b[4];
#pragma unroll
    for (int j = 0; j < 4; ++j) b[j] = *(const frag_ab*)(Bb + offB[j]);
#pragma unroll
    for (int i = 0; i < 8; ++i) a[i] = *(const frag_ab*)(Ab + offA[i]);

    __builtin_amdgcn_s_setprio(1);
#pragma unroll
    for (int i = 0; i < 8; ++i)
#pragma unroll
      for (int j = 0; j < 4; ++j)
        acc[i][j] = __builtin_amdgcn_mfma_f32_16x16x32_bf16(
            a[i], b[j], acc[i][j], 0, 0, 0);
    __builtin_amdgcn_s_setprio(0);
  }

  // Epilogue: out[r][c] = x_sq[r] + c_sq[c] - 2*dot.
  // C/D layout: col = lane&15, row = quad*4 + reg (m89-verified).
  float cs[4];
#pragma unroll
  for (int j = 0; j < 4; ++j) cs[j] = c_sq[m0 + wn * 64 + j * 16 + lane15];

#pragma unroll
  for (int i = 0; i < 8; ++i) {
#pragma unroll
    for (int reg = 0; reg < 4; ++reg) {
      const int r = n0 + wm * 128 + i * 16 + quad * 4 + reg;
      const float xv = x_sq[r];
      float* orow = out + (size_t)r * M_ROWS + m0 + wn * 64 + lane15;
#pragma unroll
      for (int j = 0; j < 4; ++j) {
        orow[j * 16] = xv + cs[j] - 2.0f * acc[i][j][reg];
      }
    }
  }
}

extern "C" void kernel_launch(void* const* d_in, const int* in_sizes, int n_in,
                              void* d_out, int out_size, void* d_ws, size_t ws_size,
                              hipStream_t stream) {
  const float* input   = (const float*)d_in[0];
  const float* centres = (const float*)d_in[1];
  float* out = (float*)d_out;

  // Workspace layout (~20.1 MB):
  //   a_bf: N*D bf16 (16 MiB) | b_bf: M*D bf16 (4 MiB) | x_sq: N f32 | c_sq: M f32
  char* ws = (char*)d_ws;
  unsigned short* a_bf = (unsigned short*)ws;
  unsigned short* b_bf = (unsigned short*)(ws + (size_t)N_ROWS * DDIM * 2);
  float* x_sq = (float*)(ws + (size_t)N_ROWS * DDIM * 2 + (size_t)M_ROWS * DDIM * 2);
  float* c_sq = x_sq + N_ROWS;

  rbf_convert_kernel<<<(N_ROWS + M_ROWS) / 4, 256, 0, stream>>>(
      input, centres, a_bf, b_bf, x_sq, c_sq);

  rbf_gemm_kernel<<<(N_ROWS / 256) * (M_ROWS / 256), 512, 0, stream>>>(
      a_bf, b_bf, x_sq, c_sq, out);
}